// Round 1
// 1004.663 us; speedup vs baseline: 1.0240x; 1.0240x over previous
//
#include <hip/hip_runtime.h>
#include <hip/hip_bf16.h>
#include <stdint.h>

typedef __bf16 bf16_t;
typedef __bf16 bf16x2 __attribute__((ext_vector_type(2)));
typedef __bf16 bf16x8 __attribute__((ext_vector_type(8)));
typedef float f32x4 __attribute__((ext_vector_type(4)));

#define NB 256
#define NS 256
#define NE 384
#define NH 6
#define ND 64
#define NM (NB*NS)   // 65536 rows

__device__ __forceinline__ f32x4 mfma16(bf16x8 a, bf16x8 b, f32x4 c) {
    return __builtin_amdgcn_mfma_f32_16x16x32_bf16(a, b, c, 0, 0, 0);
}

__device__ __forceinline__ void cp16_async(const bf16_t* g, const bf16_t* l) {
    __builtin_amdgcn_global_load_lds(
        (__attribute__((address_space(1))) void*)g,
        (__attribute__((address_space(3))) void*)l, 16, 0, 0);
}

// ---------------- weight prep ----------------
// QKV concat: Wcat[n][e], n = sel*384 + h*64 + d, value = W{sel}[h][e][d]
__global__ void wqkv_trans(const float* __restrict__ Wq, const float* __restrict__ Wk,
                           const float* __restrict__ Wv, bf16_t* __restrict__ Wcat)
{
    int i = blockIdx.x * 256 + threadIdx.x;   // over H*E*DH = 147456
    if (i >= NH*NE*ND) return;
    int d = i & 63;
    int e = (i >> 6) % NE;
    int h = i / (NE*ND);
    int n = h*64 + d;
    Wcat[(size_t)(0*NE*NH*ND) + (size_t)n*NE + e]            = (bf16_t)Wq[i];
    Wcat[(size_t)(NE)*(NH*ND) + (size_t)(384 + n)*NE + e - (size_t)(NE)*(NH*ND)] = (bf16_t)Wk[i]; // = Wcat[(384+n)*NE+e]
    Wcat[(size_t)(768 + n)*NE + e]                            = (bf16_t)Wv[i];
}

__global__ void wtrans(const float* __restrict__ src, bf16_t* __restrict__ dst, int K, int N)
{
    int i = blockIdx.x * 256 + threadIdx.x;   // over K*N
    if (i >= K*N) return;
    int k = i / N, n = i % N;
    dst[(size_t)n*K + k] = (bf16_t)src[i];
}

// ---------------- layernorm: one wave per row of 384 ----------------
__global__ __launch_bounds__(256) void ln_kernel(
    const float* __restrict__ x, const float* __restrict__ g,
    const float* __restrict__ be, bf16_t* __restrict__ o)
{
    const int wave = threadIdx.x >> 6, lane = threadIdx.x & 63;
    const int row = blockIdx.x * 4 + wave;
    const float* xr = x + (size_t)row * NE;
    float v[6]; float s = 0.f, sq = 0.f;
    #pragma unroll
    for (int i = 0; i < 6; i++) { v[i] = xr[i*64 + lane]; s += v[i]; sq += v[i]*v[i]; }
    #pragma unroll
    for (int off = 32; off > 0; off >>= 1) { s += __shfl_xor(s, off); sq += __shfl_xor(sq, off); }
    const float mean = s * (1.f/NE);
    const float rstd = rsqrtf(sq * (1.f/NE) - mean*mean + 1e-5f);
    bf16_t* orow = o + (size_t)row * NE;
    #pragma unroll
    for (int i = 0; i < 6; i++) {
        int e = i*64 + lane;
        orow[e] = (bf16_t)((v[i] - mean) * rstd * g[e] + be[e]);
    }
}

// ---------------- bf16 MFMA GEMM, B transposed (N x K rows, row stride ldb), double-buffered ----------------
// OUT_MODE: 1 = bf16 scattered to qkv [sel][b][h][s][d], 2 = fp32 row-major, 3 = bf16 row-major
template<int OUT_MODE, bool RELU>
__global__ __launch_bounds__(256, 2) void gemm_bt(
    const bf16_t* __restrict__ A, const bf16_t* __restrict__ Bt,
    void* __restrict__ outp, const float* __restrict__ bias,
    const float* __restrict__ res, int M, int N, int K, int ldb)
{
    __shared__ bf16_t sA[2][128*32];
    __shared__ bf16_t sB[2][128*32];
    const int tid = threadIdx.x;
    const int wave = tid >> 6, lane = tid & 63;
    const int l15 = lane & 15, quad = lane >> 4;
    const int m0 = blockIdx.x * 128;
    const int n0 = blockIdx.y * 128;
    const int wm = wave >> 1, wn = wave & 1;

    const int srow = lane >> 2;
    const int scol = (lane & 3) * 8;
    const bf16_t* gA = A  + (size_t)(m0 + 32*wave + srow) * K + scol;
    const bf16_t* gB = Bt + (size_t)(n0 + 32*wave + srow) * ldb + scol;

    const f32x4 zero = {0.f, 0.f, 0.f, 0.f};
    f32x4 acc[4][4];
    #pragma unroll
    for (int a = 0; a < 4; a++)
        #pragma unroll
        for (int b = 0; b < 4; b++) acc[a][b] = zero;

    const int nk = K >> 5;
    // preload tile 0 into buffer 0
    cp16_async(gA, &sA[0][(32*wave)*32]);
    cp16_async(gA + (size_t)16*K, &sA[0][(32*wave + 16)*32]);
    cp16_async(gB, &sB[0][(32*wave)*32]);
    cp16_async(gB + (size_t)16*ldb, &sB[0][(32*wave + 16)*32]);

    for (int it = 0; it < nk; it++) {
        __syncthreads();   // drains vmcnt: buf[it&1] staged; prev compute done
        if (it + 1 < nk) {
            int kt = (it + 1) << 5;
            int nb = (it + 1) & 1;
            cp16_async(gA + kt, &sA[nb][(32*wave)*32]);
            cp16_async(gA + (size_t)16*K + kt, &sA[nb][(32*wave + 16)*32]);
            cp16_async(gB + kt, &sB[nb][(32*wave)*32]);
            cp16_async(gB + (size_t)16*ldb + kt, &sB[nb][(32*wave + 16)*32]);
        }
        const int cb = it & 1;
        bf16x8 af[4], bfr[4];
        #pragma unroll
        for (int i = 0; i < 4; i++)
            af[i] = *(const bf16x8*)&sA[cb][(64*wm + 16*i + l15)*32 + quad*8];
        #pragma unroll
        for (int i = 0; i < 4; i++)
            bfr[i] = *(const bf16x8*)&sB[cb][(64*wn + 16*i + l15)*32 + quad*8];
        #pragma unroll
        for (int mi = 0; mi < 4; mi++)
            #pragma unroll
            for (int ni = 0; ni < 4; ni++)
                acc[mi][ni] = mfma16(af[mi], bfr[ni], acc[mi][ni]);
    }

    #pragma unroll
    for (int mi = 0; mi < 4; mi++) {
        #pragma unroll
        for (int ni = 0; ni < 4; ni++) {
            #pragma unroll
            for (int r = 0; r < 4; r++) {
                int gm = m0 + 64*wm + 16*mi + quad*4 + r;
                int gn = n0 + 64*wn + 16*ni + l15;
                float v = acc[mi][ni][r];
                if (bias) v += bias[gn];
                if (res)  v += res[(size_t)gm*N + gn];
                if (RELU) v = fmaxf(v, 0.f);
                if (OUT_MODE == 1) {
                    int sel = (gn >= 768) ? 2 : ((gn >= 384) ? 1 : 0);
                    int within = gn - sel*384;
                    int b = gm >> 8, s = gm & 255, h = within >> 6, d = within & 63;
                    ((bf16_t*)outp)[(size_t)sel*((size_t)NM*384) +
                                    (((size_t)b*NH + h)*NS + s)*ND + d] = (bf16_t)v;
                } else if (OUT_MODE == 2) {
                    ((float*)outp)[(size_t)gm*N + gn] = v;
                } else {
                    ((bf16_t*)outp)[(size_t)gm*N + gn] = (bf16_t)v;
                }
            }
        }
    }
}

// ---------------- fused causal attention: one block per (b,h) ----------------
__global__ __launch_bounds__(256) void attn_kernel(
    const bf16_t* __restrict__ Qg, const bf16_t* __restrict__ Kg,
    const bf16_t* __restrict__ Vg, bf16_t* __restrict__ Og)
{
    __shared__ bf16_t sK[256*72];    // [t][72] padded
    __shared__ bf16_t sVT[64*264];   // [d][264] padded (V transposed)
    __shared__ bf16_t sQ[64*72];     // current 64-row Q tile
    __shared__ bf16_t sS[64*264];    // scores, then unnormalized P
    __shared__ float sMax[64*4];
    __shared__ float sSum[64*4];
    __shared__ float sRowSum[64];

    const int tid = threadIdx.x;
    const int wave = tid >> 6, lane = tid & 63;
    const int l15 = lane & 15, quad = lane >> 4;
    const int bh = blockIdx.x;
    const int b = bh / NH, h = bh % NH;
    const size_t base = (size_t)bh * (NS*ND);
    const bf16_t* Qb = Qg + base;
    const bf16_t* Kb = Kg + base;
    const bf16_t* Vb = Vg + base;

    #pragma unroll
    for (int it = 0; it < 8; it++) {
        int idx = it*256 + tid;        // 0..2047
        int t = idx >> 3, c = idx & 7;
        bf16x8 kv = *(const bf16x8*)(Kb + t*64 + c*8);
        *(bf16x8*)&sK[t*72 + c*8] = kv;
        bf16x8 vv = *(const bf16x8*)(Vb + t*64 + c*8);
        #pragma unroll
        for (int j = 0; j < 8; j++) sVT[(c*8 + j)*264 + t] = vv[j];
    }

    const int r = lane;
    const int p = wave;
    const f32x4 zero = {0.f, 0.f, 0.f, 0.f};

    for (int mt = 0; mt < 4; mt++) {
        __syncthreads();
        #pragma unroll
        for (int it = 0; it < 2; it++) {
            int idx = it*256 + tid;
            int qr = idx >> 3, c = idx & 7;
            *(bf16x8*)&sQ[qr*72 + c*8] = *(const bf16x8*)(Qb + (64*mt + qr)*64 + c*8);
        }
        __syncthreads();
        if (wave <= mt) {
            const int ct = wave;
            bf16x8 bk[2][4];
            #pragma unroll
            for (int ks = 0; ks < 2; ks++)
                #pragma unroll
                for (int ni = 0; ni < 4; ni++)
                    bk[ks][ni] = *(const bf16x8*)&sK[(64*ct + 16*ni + l15)*72 + ks*32 + quad*8];
            #pragma unroll
            for (int mi = 0; mi < 4; mi++) {
                bf16x8 a0 = *(const bf16x8*)&sQ[(16*mi + l15)*72 + quad*8];
                bf16x8 a1 = *(const bf16x8*)&sQ[(16*mi + l15)*72 + 32 + quad*8];
                f32x4 sc[4];
                #pragma unroll
                for (int ni = 0; ni < 4; ni++) sc[ni] = zero;
                #pragma unroll
                for (int ni = 0; ni < 4; ni++) sc[ni] = mfma16(a0, bk[0][ni], sc[ni]);
                #pragma unroll
                for (int ni = 0; ni < 4; ni++) sc[ni] = mfma16(a1, bk[1][ni], sc[ni]);
                #pragma unroll
                for (int ni = 0; ni < 4; ni++)
                    #pragma unroll
                    for (int rr = 0; rr < 4; rr++)
                        sS[(16*mi + quad*4 + rr)*264 + 64*ct + 16*ni + l15] =
                            (bf16_t)(sc[ni][rr] * 0.125f);
            }
        }
        __syncthreads();
        const int sg = 64*mt + r;
        float mx = -INFINITY;
        if (p <= mt) {
            #pragma unroll
            for (int c = 0; c < 8; c++) {
                bf16x8 v8 = *(const bf16x8*)&sS[r*264 + 64*p + c*8];
                #pragma unroll
                for (int j = 0; j < 8; j++) {
                    int t = 64*p + c*8 + j;
                    float v = (float)v8[j];
                    mx = (t <= sg) ? fmaxf(mx, v) : mx;
                }
            }
        }
        sMax[r*4 + p] = mx;
        __syncthreads();
        const float rmax = fmaxf(fmaxf(sMax[r*4+0], sMax[r*4+1]),
                                 fmaxf(sMax[r*4+2], sMax[r*4+3]));
        float sum = 0.f;
        if (p <= mt) {
            #pragma unroll
            for (int c = 0; c < 8; c++) {
                bf16x8 v8 = *(const bf16x8*)&sS[r*264 + 64*p + c*8];
                bf16x8 e8;
                #pragma unroll
                for (int j = 0; j < 8; j++) {
                    int t = 64*p + c*8 + j;
                    float e = 0.f;
                    if (t <= sg) e = __expf((float)v8[j] - rmax);
                    sum += e;
                    e8[j] = (bf16_t)e;
                }
                *(bf16x8*)&sS[r*264 + 64*p + c*8] = e8;
            }
        }
        sSum[r*4 + p] = sum;
        __syncthreads();
        if (p == 0) sRowSum[r] = sSum[r*4+0] + sSum[r*4+1] + sSum[r*4+2] + sSum[r*4+3];
        __syncthreads();
        f32x4 oacc[4];
        #pragma unroll
        for (int ni = 0; ni < 4; ni++) oacc[ni] = zero;
        for (int kt = 0; kt <= mt; kt++) {
            bf16x8 a = *(const bf16x8*)&sS[(16*p + l15)*264 + 64*kt + quad*8];
            #pragma unroll
            for (int ni = 0; ni < 4; ni++) {
                bf16x8 bv = *(const bf16x8*)&sVT[(16*ni + l15)*264 + 64*kt + quad*8];
                oacc[ni] = mfma16(a, bv, oacc[ni]);
            }
        }
        #pragma unroll
        for (int ni = 0; ni < 4; ni++) {
            #pragma unroll
            for (int rr = 0; rr < 4; rr++) {
                int lrow = 16*p + quad*4 + rr;
                float inv = 1.0f / sRowSum[lrow];
                int srow_g = 64*mt + lrow;
                int d = 16*ni + l15;
                Og[((size_t)(b*NS + srow_g))*NE + h*ND + d] = (bf16_t)(oacc[ni][rr] * inv);
            }
        }
    }
}

// ---------------- host launcher ----------------
extern "C" void kernel_launch(void* const* d_in, const int* in_sizes, int n_in,
                              void* d_out, int out_size, void* d_ws, size_t ws_size,
                              hipStream_t stream)
{
    (void)in_sizes; (void)n_in; (void)out_size; (void)ws_size;
    const float* x   = (const float*)d_in[0];
    const float* Wq  = (const float*)d_in[1];
    const float* Wk  = (const float*)d_in[2];
    const float* Wv  = (const float*)d_in[3];
    const float* Wp  = (const float*)d_in[4];
    const float* bp  = (const float*)d_in[5];
    const float* W1  = (const float*)d_in[6];
    const float* b1  = (const float*)d_in[7];
    const float* W2  = (const float*)d_in[8];
    const float* b2  = (const float*)d_in[9];
    const float* g1  = (const float*)d_in[10];
    const float* be1 = (const float*)d_in[11];
    const float* g2  = (const float*)d_in[12];
    const float* be2 = (const float*)d_in[13];
    float* out = (float*)d_out;

    char* ws = (char*)d_ws;
    const size_t SZ = (size_t)NM * NE * 2;           // 48 MiB per bf16 activation
    bf16_t* h_bf  = (bf16_t*)(ws);                   // dead after QKV GEMM
    bf16_t* q_bf  = (bf16_t*)(ws + SZ);              // qkv contiguous: q,k,v
    bf16_t* k_bf  = (bf16_t*)(ws + 2*SZ);
    bf16_t* v_bf  = (bf16_t*)(ws + 3*SZ);
    bf16_t* o_bf  = (bf16_t*)(ws);                   // overlay h (h dead)
    bf16_t* h2_bf = (bf16_t*)(ws);                   // overlay o (o dead after proj)
    bf16_t* hid   = (bf16_t*)(ws + SZ);              // 96 MiB half-hidden, overlays dead q/k
    char* wb = ws + 4*SZ;
    bf16_t* Wcat = (bf16_t*)(wb);                    // 1152*384*2 = 884736
    bf16_t* Wpt  = (bf16_t*)(wb + 884736);
    bf16_t* W1t  = (bf16_t*)(wb + 884736 + 294912);
    bf16_t* W2t  = (bf16_t*)(wb + 884736 + 294912 + 1179648);

    wqkv_trans<<<(NH*NE*ND + 255)/256, 256, 0, stream>>>(Wq, Wk, Wv, Wcat);
    wtrans<<<(NE*NE + 255)/256, 256, 0, stream>>>(Wp, Wpt, NE, NE);
    wtrans<<<(NE*4*NE + 255)/256, 256, 0, stream>>>(W1, W1t, NE, 4*NE);
    wtrans<<<(NE*4*NE + 255)/256, 256, 0, stream>>>(W2, W2t, 4*NE, NE);

    ln_kernel<<<NM/4, 256, 0, stream>>>(x, g1, be1, h_bf);

    dim3 gqkv(NM/128, 9), g384(NM/128, 3), gffn(NM/128, 6);
    gemm_bt<1,false><<<gqkv, 256, 0, stream>>>(h_bf, Wcat, q_bf, nullptr, nullptr, NM, 1152, NE, NE);

    attn_kernel<<<NB*NH, 256, 0, stream>>>(q_bf, k_bf, v_bf, o_bf);

    gemm_bt<2,false><<<g384, 256, 0, stream>>>(o_bf, Wpt, out, bp, x, NM, NE, NE, NE);

    // ---- FFN as two half-hidden (768-col) passes through the tuned GEMM ----
    ln_kernel<<<NM/4, 256, 0, stream>>>(out, g2, be2, h2_bf);

    // half 1: hid = relu(h2 @ W1[:, 0:768] + b1[0:768]); out += hid @ W2[0:768, :] + b2
    gemm_bt<3,true ><<<gffn, 256, 0, stream>>>(h2_bf, W1t, hid, b1, nullptr, NM, 768, NE, NE);
    gemm_bt<2,false><<<g384, 256, 0, stream>>>(hid, W2t, out, b2, out, NM, NE, 768, 1536);

    // half 2: hid = relu(h2 @ W1[:, 768:1536] + b1[768:1536]); out += hid @ W2[768:1536, :]
    gemm_bt<3,true ><<<gffn, 256, 0, stream>>>(h2_bf, W1t + (size_t)768*NE, hid, b1 + 768, nullptr, NM, 768, NE, NE);
    gemm_bt<2,false><<<g384, 256, 0, stream>>>(hid, W2t + 768, out, nullptr, out, NM, NE, 768, 1536);
}